// Round 8
// baseline (131.461 us; speedup 1.0000x reference)
//
#include <hip/hip_runtime.h>

#define BATCH 4
#define CTX   2048
#define EMB   1024
#define HEAD  128

typedef __attribute__((ext_vector_type(8))) short bf16x8;
typedef __attribute__((ext_vector_type(4))) float f32x4;
typedef const __attribute__((address_space(1))) unsigned int* gas_t;
typedef __attribute__((address_space(3))) unsigned int* las_t;

#define FINF (__builtin_inff())
__device__ inline float fexp2(float x) { return __builtin_amdgcn_exp2f(x); }

// async global->LDS, 16B per lane. LDS dest = wave-uniform base + lane*16.
__device__ inline void cp16(const void* g, void* l) {
    __builtin_amdgcn_global_load_lds((gas_t)g, (las_t)l, 16, 0, 0);
}

__device__ inline unsigned short f2bf(float f) {
    union { float f; unsigned u; } v; v.f = f;
    unsigned r = v.u + 0x7fffu + ((v.u >> 16) & 1u);
    return (unsigned short)(r >> 16);
}
__device__ inline unsigned pk2(float a, float b) {
    return (unsigned)f2bf(a) | ((unsigned)f2bf(b) << 16);
}
__device__ inline float bf2f(unsigned u16) {
    union { unsigned u; float f; } v; v.u = u16 << 16; return v.f;
}

// ---------------------------------------------------------------------------
// W[1024][128] fp32 -> Wt[w][128][1024] bf16 (transposed). grid (16,2,3).
// ---------------------------------------------------------------------------
__global__ __launch_bounds__(256)
void transpose_w_kernel(const float* __restrict__ Wq, const float* __restrict__ Wk,
                        const float* __restrict__ Wv, unsigned short* __restrict__ Wt) {
    const int k0 = blockIdx.x * 64;
    const int h0 = blockIdx.y * 64;
    const int w  = blockIdx.z;
    const float* W = (w == 0) ? Wq : (w == 1) ? Wk : Wv;
    __shared__ float Ts[64][65];
    const int tid = threadIdx.x;
    #pragma unroll
    for (int it = 0; it < 4; ++it) {
        const int kk = (tid >> 4) + it * 16;
        const int c4 = (tid & 15) * 4;
        const float4 f = *(const float4*)&W[(size_t)(k0 + kk) * HEAD + h0 + c4];
        Ts[kk][c4 + 0] = f.x; Ts[kk][c4 + 1] = f.y;
        Ts[kk][c4 + 2] = f.z; Ts[kk][c4 + 3] = f.w;
    }
    __syncthreads();
    const int hr  = tid >> 2;
    const int kc0 = (tid & 3) * 16;
    union { unsigned short s[16]; uint4 q[2]; } tmp;
    #pragma unroll
    for (int i = 0; i < 16; ++i) tmp.s[i] = f2bf(Ts[kc0 + i][hr]);
    unsigned short* dst = &Wt[(size_t)w * HEAD * EMB + (size_t)(h0 + hr) * EMB + k0 + kc0];
    ((uint4*)dst)[0] = tmp.q[0];
    ((uint4*)dst)[1] = tmp.q[1];
}

// ---------------------------------------------------------------------------
// QKV projection: LDS double-buffered MFMA GEMM (unchanged from R6/R7).
// ---------------------------------------------------------------------------
__global__ __launch_bounds__(128, 3)
void proj_kernel(const float* __restrict__ x, const unsigned short* __restrict__ Wt,
                 unsigned short* __restrict__ qb, unsigned short* __restrict__ kb,
                 unsigned short* __restrict__ vt) {
    __shared__ __align__(16) char smem[24576];
    char* Ab = smem;            // 2 x 4KB : x tile [32 tok][32 k] fp32
    char* Bb = smem + 8192;     // 2 x 8KB : W tile [128 h][32 k] bf16

    const int wsel = blockIdx.y;
    const int tid  = threadIdx.x;
    const int wv   = tid >> 6;
    const int lane = tid & 63;
    const int p = lane >> 4, c = lane & 15;
    const int m0 = blockIdx.x * 32;
    const unsigned short* Wp = Wt + (size_t)wsel * HEAD * EMB;

    const int u7  = c & 7;
    const int u2c = (c ^ (c >> 2)) & 3;

    auto stage = [&](int bi, int ks) {
        #pragma unroll
        for (int i = 0; i < 2; ++i) {      // A: 32 rows x 128B
            const int f = i * 128 + tid;
            const int r = f >> 3, s = f & 7, q = s ^ (r & 7);
            cp16(&x[(size_t)(m0 + r) * EMB + ks * 32 + q * 4],
                 Ab + bi * 4096 + i * 2048 + wv * 1024);
        }
        #pragma unroll
        for (int i = 0; i < 4; ++i) {      // B: 128 rows x 64B
            const int f = i * 128 + tid;
            const int h = f >> 2, s = f & 3, q = s ^ ((h ^ (h >> 2)) & 3);
            cp16(&Wp[(size_t)h * EMB + ks * 32 + q * 8],
                 Bb + bi * 8192 + i * 2048 + wv * 1024);
        }
    };
    auto xfrag = [&](const char* Ac, int r) {
        const float4 a0 = *(const float4*)(Ac + r * 128 + (((2 * p)     ^ u7) * 16));
        const float4 a1 = *(const float4*)(Ac + r * 128 + (((2 * p + 1) ^ u7) * 16));
        union { unsigned u[4]; bf16x8 v; } xf;
        xf.u[0] = pk2(a0.x, a0.y); xf.u[1] = pk2(a0.z, a0.w);
        xf.u[2] = pk2(a1.x, a1.y); xf.u[3] = pk2(a1.z, a1.w);
        return xf.v;
    };

    if (wsel < 2) {
        f32x4 acc[8];
        #pragma unroll
        for (int i = 0; i < 8; ++i) acc[i] = (f32x4){0.f, 0.f, 0.f, 0.f};
        stage(0, 0);
        for (int ks = 0; ks < 32; ++ks) {
            const int cur = ks & 1;
            __syncthreads();
            if (ks + 1 < 32) stage(cur ^ 1, ks + 1);
            const bf16x8 xv = xfrag(Ab + cur * 4096, wv * 16 + c);
            const char* Bc = Bb + cur * 8192;
            #pragma unroll
            for (int nt = 0; nt < 8; ++nt) {
                const int h = nt * 16 + c;
                const bf16x8 wf = *(const bf16x8*)(Bc + h * 64 + ((p ^ u2c) * 16));
                acc[nt] = __builtin_amdgcn_mfma_f32_16x16x32_bf16(xv, wf, acc[nt], 0, 0, 0);
            }
        }
        unsigned short* outp = (wsel == 0) ? qb : kb;
        #pragma unroll
        for (int rr = 0; rr < 4; ++rr) {
            unsigned short* orow = outp + (size_t)(m0 + wv * 16 + p * 4 + rr) * HEAD + c;
            #pragma unroll
            for (int nt = 0; nt < 8; ++nt)
                orow[nt * 16] = f2bf(acc[nt][rr]);
        }
    } else {
        f32x4 acc[4][2];
        #pragma unroll
        for (int i = 0; i < 4; ++i)
            #pragma unroll
            for (int j = 0; j < 2; ++j) acc[i][j] = (f32x4){0.f, 0.f, 0.f, 0.f};
        stage(0, 0);
        for (int ks = 0; ks < 32; ++ks) {
            const int cur = ks & 1;
            __syncthreads();
            if (ks + 1 < 32) stage(cur ^ 1, ks + 1);
            const char* Ac = Ab + cur * 4096;
            const char* Bc = Bb + cur * 8192;
            bf16x8 xv[2];
            #pragma unroll
            for (int n2 = 0; n2 < 2; ++n2) xv[n2] = xfrag(Ac, n2 * 16 + c);
            #pragma unroll
            for (int mt = 0; mt < 4; ++mt) {
                const int h = wv * 64 + mt * 16 + c;
                const bf16x8 wf = *(const bf16x8*)(Bc + h * 64 + ((p ^ u2c) * 16));
                #pragma unroll
                for (int n2 = 0; n2 < 2; ++n2)
                    acc[mt][n2] = __builtin_amdgcn_mfma_f32_16x16x32_bf16(wf, xv[n2], acc[mt][n2], 0, 0, 0);
            }
        }
        const int bidx = m0 >> 11;
        const int tl   = m0 & (CTX - 1);
        unsigned short* vbp = vt + (size_t)bidx * HEAD * CTX;
        #pragma unroll
        for (int mt = 0; mt < 4; ++mt)
            #pragma unroll
            for (int rr = 0; rr < 4; ++rr) {
                const int h = wv * 64 + mt * 16 + p * 4 + rr;
                #pragma unroll
                for (int n2 = 0; n2 < 2; ++n2)
                    vbp[(size_t)h * CTX + tl + n2 * 16 + c] = f2bf(acc[mt][n2][rr]);
            }
    }
}

// ---------------------------------------------------------------------------
// Split-KV flash attention v2. Block = 128 threads (2 waves); wave owns 32
// q rows (2 stacks of 16); block tile = 64 q rows. Chunk = 256 kv (<=4 steps
// of 64). Halves per-q-row LDS-read redundancy vs R7 (2 waves share staged
// K/V instead of 4) and raises grid to 576 blocks (2.25/CU, 2 co-resident).
// Tile T (0..31, 64 rows) has nch = T/4+1 chunks; partials -> pO/pM/pL.
// ---------------------------------------------------------------------------
__global__ __launch_bounds__(128, 1)
void attn_split_kernel(const unsigned short* __restrict__ qb,
                       const unsigned short* __restrict__ kb,
                       const unsigned short* __restrict__ vt,
                       unsigned short* __restrict__ pO,
                       float* __restrict__ pM, float* __restrict__ pL) {
    __shared__ __align__(16) char smem[65536];
    char* Kb = smem;            // 2 x 16KB : [64 kv][128 h] bf16
    char* Vb = smem + 32768;    // 2 x 16KB : [128 h][64 kv] bf16

    // decode blockIdx.x (0..143) -> (T, ch):  cum(4a+b) = 2a(a+1) + b(a+1)
    const int g = blockIdx.x;
    const int b = blockIdx.y;
    int a = 0;
    while (a < 7 && g >= 2 * (a + 1) * (a + 2)) ++a;
    const int rem = g - 2 * a * (a + 1);
    const int T   = 4 * a + rem / (a + 1);
    const int ch  = rem % (a + 1);
    const bool lastchunk = (ch == a);          // nch = a+1
    const int kstart = ch * 256;
    const int nsteps = lastchunk ? ((T & 3) + 1) : 4;

    const int tid  = threadIdx.x;
    const int wv   = tid >> 6;
    const int lane = tid & 63;
    const int p = lane >> 4, c = lane & 15;
    const int t0 = T * 64;
    const int u7 = c & 7;
    int qg[2];
    qg[0] = t0 + wv * 32 + c;
    qg[1] = qg[0] + 16;

    const unsigned short* kbat = kb + (size_t)b * CTX * HEAD;
    const unsigned short* vbat = vt + (size_t)b * HEAD * CTX;

    bf16x8 qf[2][4];
    #pragma unroll
    for (int qs = 0; qs < 2; ++qs)
        #pragma unroll
        for (int ks = 0; ks < 4; ++ks)
            qf[qs][ks] = *(const bf16x8*)&qb[((size_t)b * CTX + t0 + wv * 32 + qs * 16 + c) * HEAD + ks * 32 + p * 8];

    f32x4 o[2][8];
    #pragma unroll
    for (int qs = 0; qs < 2; ++qs)
        #pragma unroll
        for (int i = 0; i < 8; ++i) o[qs][i] = (f32x4){0.f, 0.f, 0.f, 0.f};
    float m2[2] = {-FINF, -FINF}, l2[2] = {0.f, 0.f};

    const int  slA = 32 * (p & 1) + c;
    const int  slB = slA + 16;
    const bool thi = (p >> 1) != 0;
    const float scale2 = 0.08838834764831845f * 1.44269504088896340f;  // 1/sqrt(128)*log2e

    auto stage = [&](int bi, int js) {
        const unsigned short* kg = kbat + (size_t)(kstart + js * 64) * HEAD;
        #pragma unroll
        for (int i = 0; i < 8; ++i) {      // K: 64 rows x 256B
            const int f = i * 128 + tid;
            const int r = f >> 4, s = f & 15, q = s ^ (r & 7);
            cp16(kg + (size_t)r * HEAD + q * 8, Kb + bi * 16384 + (f >> 6) * 1024);
        }
        const unsigned short* vg = vbat + kstart + js * 64;
        #pragma unroll
        for (int i = 0; i < 8; ++i) {      // V: 128 rows x 128B
            const int f = i * 128 + tid;
            const int r = f >> 3, s = f & 7, q = s ^ (r & 7);
            cp16(vg + (size_t)r * CTX + q * 8, Vb + bi * 16384 + (f >> 6) * 1024);
        }
    };

    stage(0, 0);
    for (int js = 0; js < nsteps; ++js) {
        const int cur = js & 1;
        __builtin_amdgcn_s_waitcnt(0);
        __syncthreads();                   // buf[cur] fully staged by both waves

        bf16x8 kfr[4][4];
        #pragma unroll
        for (int nt = 0; nt < 4; ++nt) {
            const char* rp = Kb + cur * 16384 + (nt * 16 + c) * 256;
            #pragma unroll
            for (int ks = 0; ks < 4; ++ks)
                kfr[nt][ks] = *(const bf16x8*)(rp + (((ks * 4 + p) ^ u7) * 16));
        }
        if (js + 1 < nsteps) stage(cur ^ 1, js + 1);

        // S^T = K * Q^T for both q-stacks
        f32x4 st[2][4];
        #pragma unroll
        for (int qs = 0; qs < 2; ++qs)
            #pragma unroll
            for (int nt = 0; nt < 4; ++nt) st[qs][nt] = (f32x4){0.f, 0.f, 0.f, 0.f};
        #pragma unroll
        for (int ks = 0; ks < 4; ++ks)
            #pragma unroll
            for (int nt = 0; nt < 4; ++nt) {
                st[0][nt] = __builtin_amdgcn_mfma_f32_16x16x32_bf16(kfr[nt][ks], qf[0][ks], st[0][nt], 0, 0, 0);
                st[1][nt] = __builtin_amdgcn_mfma_f32_16x16x32_bf16(kfr[nt][ks], qf[1][ks], st[1][nt], 0, 0, 0);
            }

        bf16x8 vfr[2][8];
        #pragma unroll
        for (int mt = 0; mt < 8; ++mt) {
            const char* rp = Vb + cur * 16384 + (mt * 16 + c) * 128;
            #pragma unroll
            for (int c2 = 0; c2 < 2; ++c2)
                vfr[c2][mt] = *(const bf16x8*)(rp + (((c2 * 4 + p) ^ u7) * 16));
        }

        const bool domask = lastchunk && (js == nsteps - 1);
        float s[2][4][4];
        #pragma unroll
        for (int qs = 0; qs < 2; ++qs) {
            float lm = -FINF;
            if (domask) {
                #pragma unroll
                for (int nt = 0; nt < 4; ++nt)
                    #pragma unroll
                    for (int r = 0; r < 4; ++r) {
                        const int kv = kstart + js * 64 + nt * 16 + p * 4 + r;
                        float v = st[qs][nt][r] * scale2;
                        v = (kv <= qg[qs]) ? v : -FINF;
                        s[qs][nt][r] = v;
                        lm = fmaxf(lm, v);
                    }
            } else {
                #pragma unroll
                for (int nt = 0; nt < 4; ++nt)
                    #pragma unroll
                    for (int r = 0; r < 4; ++r) {
                        const float v = st[qs][nt][r] * scale2;
                        s[qs][nt][r] = v;
                        lm = fmaxf(lm, v);
                    }
            }
            lm = fmaxf(lm, __shfl_xor(lm, 16, 64));
            lm = fmaxf(lm, __shfl_xor(lm, 32, 64));
            const float m_new = fmaxf(m2[qs], lm);
            const float alpha = fexp2(m2[qs] - m_new);
            float ls = 0.f;
            #pragma unroll
            for (int nt = 0; nt < 4; ++nt)
                #pragma unroll
                for (int r = 0; r < 4; ++r) {
                    const float pv = fexp2(s[qs][nt][r] - m_new);
                    s[qs][nt][r] = pv;
                    ls += pv;
                }
            ls += __shfl_xor(ls, 16, 64);
            ls += __shfl_xor(ls, 32, 64);
            l2[qs] = l2[qs] * alpha + ls;
            m2[qs] = m_new;
            #pragma unroll
            for (int i = 0; i < 8; ++i) {
                o[qs][i][0] *= alpha; o[qs][i][1] *= alpha;
                o[qs][i][2] *= alpha; o[qs][i][3] *= alpha;
            }
            // P^T B-frags via shuffles, then O^T += V^T * P^T
            #pragma unroll
            for (int c2 = 0; c2 < 2; ++c2) {
                const unsigned pa0 = pk2(s[qs][2*c2][0],     s[qs][2*c2][1]);
                const unsigned pb0 = pk2(s[qs][2*c2][2],     s[qs][2*c2][3]);
                const unsigned pa1 = pk2(s[qs][2*c2 + 1][0], s[qs][2*c2 + 1][1]);
                const unsigned pb1 = pk2(s[qs][2*c2 + 1][2], s[qs][2*c2 + 1][3]);
                const unsigned u0a = __shfl((int)pa0, slA, 64), u0b = __shfl((int)pa1, slA, 64);
                const unsigned u1a = __shfl((int)pb0, slA, 64), u1b = __shfl((int)pb1, slA, 64);
                const unsigned u2a = __shfl((int)pa0, slB, 64), u2b = __shfl((int)pa1, slB, 64);
                const unsigned u3a = __shfl((int)pb0, slB, 64), u3b = __shfl((int)pb1, slB, 64);
                union { unsigned u[4]; bf16x8 v; } pf;
                pf.u[0] = thi ? u0b : u0a;
                pf.u[1] = thi ? u1b : u1a;
                pf.u[2] = thi ? u2b : u2a;
                pf.u[3] = thi ? u3b : u3a;
                #pragma unroll
                for (int mt = 0; mt < 8; ++mt)
                    o[qs][mt] = __builtin_amdgcn_mfma_f32_16x16x32_bf16(vfr[c2][mt], pf.v, o[qs][mt], 0, 0, 0);
            }
        }
    }

    // partial store: row = wv*32 + qs*16 + c, col = mt*16 + p*4 + r
    const size_t pbase = (size_t)(b * 32 + T) * 8 + ch;
    unsigned short* po = pO + pbase * (64 * 128);
    #pragma unroll
    for (int qs = 0; qs < 2; ++qs) {
        unsigned short* prow = po + (wv * 32 + qs * 16 + c) * 128;
        #pragma unroll
        for (int mt = 0; mt < 8; ++mt) {
            union { unsigned short sh[4]; uint2 u; } t;
            #pragma unroll
            for (int r = 0; r < 4; ++r) t.sh[r] = f2bf(o[qs][mt][r]);
            *(uint2*)&prow[mt * 16 + p * 4] = t.u;
        }
        if (p == 0) {
            pM[pbase * 64 + wv * 32 + qs * 16 + c] = m2[qs];
            pL[pbase * 64 + wv * 32 + qs * 16 + c] = l2[qs];
        }
    }
}

// ---------------------------------------------------------------------------
// Merge up to 8 partial chunks: out = sum_i w_i O_i / sum_i w_i l_i,
// w_i = 2^(m_i - M).  grid (32, 4), 256 threads: row = tid>>2, 32 cols.
// ---------------------------------------------------------------------------
__global__ __launch_bounds__(256)
void attn_merge_kernel(const unsigned short* __restrict__ pO,
                       const float* __restrict__ pM, const float* __restrict__ pL,
                       float* __restrict__ out) {
    const int T = blockIdx.x, b = blockIdx.y;
    const int nch = (T >> 2) + 1;
    const int tid = threadIdx.x;
    const int r   = tid >> 2;
    const int c0  = (tid & 3) * 32;
    const size_t base = (size_t)(b * 32 + T) * 8;

    float mv[8], lv[8];
    float M = -FINF;
    #pragma unroll
    for (int i = 0; i < 8; ++i) {
        if (i < nch) { mv[i] = pM[(base + i) * 64 + r]; lv[i] = pL[(base + i) * 64 + r]; }
        else         { mv[i] = -FINF;                   lv[i] = 0.f; }
        M = fmaxf(M, mv[i]);
    }
    float w[8], L = 0.f;
    #pragma unroll
    for (int i = 0; i < 8; ++i) { w[i] = fexp2(mv[i] - M); L += w[i] * lv[i]; }
    const float inv = 1.f / L;

    float acc[32];
    #pragma unroll
    for (int j = 0; j < 32; ++j) acc[j] = 0.f;
    #pragma unroll
    for (int i = 0; i < 8; ++i) {
        if (i < nch) {                        // nch uniform per block: no divergence
            const unsigned* s32 = (const unsigned*)(pO + (base + i) * (64 * 128) + r * 128 + c0);
            const float wi = w[i];
            #pragma unroll
            for (int jw = 0; jw < 16; ++jw) {
                const unsigned u = s32[jw];
                acc[2 * jw]     += wi * bf2f(u & 0xffffu);
                acc[2 * jw + 1] += wi * bf2f(u >> 16);
            }
        }
    }
    float* orow = out + ((size_t)b * CTX + T * 64 + r) * HEAD + c0;
    #pragma unroll
    for (int j4 = 0; j4 < 8; ++j4) {
        float4 ov = make_float4(acc[4*j4] * inv, acc[4*j4+1] * inv,
                                acc[4*j4+2] * inv, acc[4*j4+3] * inv);
        *(float4*)&orow[4 * j4] = ov;
    }
}

// ---------------------------------------------------------------------------
// Fallback attention (R6): single-wave blocks, used if ws too small for split.
// ---------------------------------------------------------------------------
__global__ __launch_bounds__(64, 1)
void attn_kernel(const unsigned short* __restrict__ qb,
                 const unsigned short* __restrict__ kb,
                 const unsigned short* __restrict__ vt,
                 float* __restrict__ out) {
    __shared__ __align__(16) char smem[65536];
    char* Kb = smem;
    char* Vb = smem + 32768;
    const int bx   = blockIdx.x;
    const int b    = bx & 3;
    const int tile = 127 - (bx >> 2);
    const int lane = threadIdx.x;
    const int p = lane >> 4, c = lane & 15;
    const int t0 = tile * 16;
    const int qg = t0 + c;
    const int u7 = c & 7;
    const unsigned short* kbat = kb + (size_t)b * CTX * HEAD;
    const unsigned short* vbat = vt + (size_t)b * HEAD * CTX;
    bf16x8 qf[4];
    #pragma unroll
    for (int ks = 0; ks < 4; ++ks)
        qf[ks] = *(const bf16x8*)&qb[((size_t)b * CTX + t0 + c) * HEAD + ks * 32 + p * 8];
    f32x4 o[8];
    #pragma unroll
    for (int i = 0; i < 8; ++i) o[i] = (f32x4){0.f, 0.f, 0.f, 0.f};
    float m = -FINF, l = 0.f;
    const int  slA = 32 * (p & 1) + c;
    const int  slB = slA + 16;
    const bool thi = (p >> 1) != 0;
    const int  nsteps = (tile + 4) >> 2;
    const float scale2 = 0.08838834764831845f * 1.44269504088896340f;
    auto stage = [&](int bi, int js) {
        const unsigned short* kg = kbat + (size_t)(js * 64) * HEAD;
        #pragma unroll
        for (int i = 0; i < 16; ++i) {
            const int f = i * 64 + lane;
            const int r = f >> 4, s = f & 15, q = s ^ (r & 7);
            cp16(kg + (size_t)r * HEAD + q * 8, Kb + bi * 16384 + i * 1024);
        }
        #pragma unroll
        for (int i = 0; i < 16; ++i) {
            const int f = i * 64 + lane;
            const int r = f >> 3, s = f & 7, q = s ^ (r & 7);
            cp16(vbat + (size_t)r * CTX + js * 64 + q * 8, Vb + bi * 16384 + i * 1024);
        }
    };
    stage(0, 0);
    for (int js = 0; js < nsteps; ++js) {
        const int cur = js & 1;
        __builtin_amdgcn_s_waitcnt(0);
        bf16x8 kfr[4][4], vfr[2][8];
        #pragma unroll
        for (int nt = 0; nt < 4; ++nt) {
            const char* rp = Kb + cur * 16384 + (nt * 16 + c) * 256;
            #pragma unroll
            for (int ks = 0; ks < 4; ++ks)
                kfr[nt][ks] = *(const bf16x8*)(rp + (((ks * 4 + p) ^ u7) * 16));
        }
        #pragma unroll
        for (int mt = 0; mt < 8; ++mt) {
            const char* rp = Vb + cur * 16384 + (mt * 16 + c) * 128;
            #pragma unroll
            for (int ch = 0; ch < 2; ++ch)
                vfr[ch][mt] = *(const bf16x8*)(rp + (((ch * 4 + p) ^ u7) * 16));
        }
        if (js + 1 < nsteps) stage(cur ^ 1, js + 1);
        const int c0 = js * 64;
        f32x4 st[4];
        #pragma unroll
        for (int nt = 0; nt < 4; ++nt) st[nt] = (f32x4){0.f, 0.f, 0.f, 0.f};
        #pragma unroll
        for (int ks = 0; ks < 4; ++ks)
            #pragma unroll
            for (int nt = 0; nt < 4; ++nt)
                st[nt] = __builtin_amdgcn_mfma_f32_16x16x32_bf16(kfr[nt][ks], qf[ks], st[nt], 0, 0, 0);
        float s[4][4];
        float lm = -FINF;
        if (js == nsteps - 1) {
            #pragma unroll
            for (int nt = 0; nt < 4; ++nt)
                #pragma unroll
                for (int r = 0; r < 4; ++r) {
                    const int kv = c0 + nt * 16 + p * 4 + r;
                    float v = st[nt][r] * scale2;
                    v = (kv <= qg) ? v : -FINF;
                    s[nt][r] = v;
                    lm = fmaxf(lm, v);
                }
        } else {
            #pragma unroll
            for (int nt = 0; nt < 4; ++nt)
                #pragma unroll
                for (int r = 0; r < 4; ++r) {
                    const float v = st[nt][r] * scale2;
                    s[nt][r] = v;
                    lm = fmaxf(lm, v);
                }
        }
        lm = fmaxf(lm, __shfl_xor(lm, 16, 64));
        lm = fmaxf(lm, __shfl_xor(lm, 32, 64));
        const float m_new = fmaxf(m, lm);
        const float alpha = fexp2(m - m_new);
        float ls = 0.f;
        #pragma unroll
        for (int nt = 0; nt < 4; ++nt)
            #pragma unroll
            for (int r = 0; r < 4; ++r) {
                const float pv = fexp2(s[nt][r] - m_new);
                s[nt][r] = pv;
                ls += pv;
            }
        ls += __shfl_xor(ls, 16, 64);
        ls += __shfl_xor(ls, 32, 64);
        l = l * alpha + ls;
        m = m_new;
        #pragma unroll
        for (int i = 0; i < 8; ++i) {
            o[i][0] *= alpha; o[i][1] *= alpha;
            o[i][2] *= alpha; o[i][3] *= alpha;
        }
        #pragma unroll
        for (int ch = 0; ch < 2; ++ch) {
            const unsigned pa0 = pk2(s[2*ch][0],     s[2*ch][1]);
            const unsigned pb0 = pk2(s[2*ch][2],     s[2*ch][3]);
            const unsigned pa1 = pk2(s[2*ch + 1][0], s[2*ch + 1][1]);
            const unsigned pb1 = pk2(s[2*ch + 1][2], s[2*ch + 1][3]);
            const unsigned u0a = __shfl((int)pa0, slA, 64), u0b = __shfl((int)pa1, slA, 64);
            const unsigned u1a = __shfl((int)pb0, slA, 64), u1b = __shfl((int)pb1, slA, 64);
            const unsigned u2a = __shfl((int)pa0, slB, 64), u2b = __shfl((int)pa1, slB, 64);
            const unsigned u3a = __shfl((int)pb0, slB, 64), u3b = __shfl((int)pb1, slB, 64);
            union { unsigned u[4]; bf16x8 v; } pf;
            pf.u[0] = thi ? u0b : u0a;
            pf.u[1] = thi ? u1b : u1a;
            pf.u[2] = thi ? u2b : u2a;
            pf.u[3] = thi ? u3b : u3a;
            #pragma unroll
            for (int mt = 0; mt < 8; ++mt)
                o[mt] = __builtin_amdgcn_mfma_f32_16x16x32_bf16(vfr[ch][mt], pf.v, o[mt], 0, 0, 0);
        }
    }
    const float linv = 1.f / l;
    float* orow = out + ((size_t)b * CTX + t0 + c) * HEAD;
    #pragma unroll
    for (int mt = 0; mt < 8; ++mt) {
        float4 ov = make_float4(o[mt][0] * linv, o[mt][1] * linv,
                                o[mt][2] * linv, o[mt][3] * linv);
        *(float4*)&orow[mt * 16 + p * 4] = ov;
    }
}

// ---------------------------------------------------------------------------
extern "C" void kernel_launch(void* const* d_in, const int* in_sizes, int n_in,
                              void* d_out, int out_size, void* d_ws, size_t ws_size,
                              hipStream_t stream) {
    const float* x  = (const float*)d_in[0];
    const float* Wq = (const float*)d_in[1];
    const float* Wk = (const float*)d_in[2];
    const float* Wv = (const float*)d_in[3];
    float* out = (float*)d_out;

    unsigned short* Wt = (unsigned short*)d_ws;                 // 3*128*1024
    unsigned short* qb = Wt + (size_t)3 * HEAD * EMB;           // 8192*128
    unsigned short* kb = qb + (size_t)BATCH * CTX * HEAD;
    unsigned short* vt = kb + (size_t)BATCH * CTX * HEAD;
    unsigned short* pO = vt + (size_t)BATCH * CTX * HEAD;       // 4*32*8*64*128 bf16
    float* pM = (float*)(pO + (size_t)BATCH * 32 * 8 * 64 * 128);
    float* pL = pM + (size_t)BATCH * 32 * 8 * 64;

    const size_t need = (size_t)((char*)(pL + BATCH * 32 * 8 * 64) - (char*)d_ws);

    transpose_w_kernel<<<dim3(16, 2, 3), 256, 0, stream>>>(Wq, Wk, Wv, Wt);
    proj_kernel<<<dim3((BATCH * CTX) / 32, 3), 128, 0, stream>>>(x, Wt, qb, kb, vt);
    if (ws_size >= need) {
        attn_split_kernel<<<dim3(144, 4), 128, 0, stream>>>(qb, kb, vt, pO, pM, pL);
        attn_merge_kernel<<<dim3(32, 4), 256, 0, stream>>>(pO, pM, pL, out);
    } else {
        attn_kernel<<<BATCH * (CTX / 16), 64, 0, stream>>>(qb, kb, vt, out);
    }
}

// Round 9
// 120.926 us; speedup vs baseline: 1.0871x; 1.0871x over previous
//
#include <hip/hip_runtime.h>

#define BATCH 4
#define CTX   2048
#define EMB   1024
#define HEAD  128

typedef __attribute__((ext_vector_type(8))) short bf16x8;
typedef __attribute__((ext_vector_type(4))) float f32x4;
typedef const __attribute__((address_space(1))) unsigned int* gas_t;
typedef __attribute__((address_space(3))) unsigned int* las_t;

#define FINF (__builtin_inff())
__device__ inline float fexp2(float x) { return __builtin_amdgcn_exp2f(x); }

// async global->LDS, 16B per lane. LDS dest = wave-uniform base + lane*16.
__device__ inline void cp16(const void* g, void* l) {
    __builtin_amdgcn_global_load_lds((gas_t)g, (las_t)l, 16, 0, 0);
}

__device__ inline unsigned short f2bf(float f) {
    union { float f; unsigned u; } v; v.f = f;
    unsigned r = v.u + 0x7fffu + ((v.u >> 16) & 1u);
    return (unsigned short)(r >> 16);
}
__device__ inline unsigned pk2(float a, float b) {
    return (unsigned)f2bf(a) | ((unsigned)f2bf(b) << 16);
}
__device__ inline float bf2f(unsigned u16) {
    union { unsigned u; float f; } v; v.u = u16 << 16; return v.f;
}

// ---------------------------------------------------------------------------
// W[1024][128] fp32 -> Wt[w][128][1024] bf16 (transposed). grid (16,2,3).
// ---------------------------------------------------------------------------
__global__ __launch_bounds__(256)
void transpose_w_kernel(const float* __restrict__ Wq, const float* __restrict__ Wk,
                        const float* __restrict__ Wv, unsigned short* __restrict__ Wt) {
    const int k0 = blockIdx.x * 64;
    const int h0 = blockIdx.y * 64;
    const int w  = blockIdx.z;
    const float* W = (w == 0) ? Wq : (w == 1) ? Wk : Wv;
    __shared__ float Ts[64][65];
    const int tid = threadIdx.x;
    #pragma unroll
    for (int it = 0; it < 4; ++it) {
        const int kk = (tid >> 4) + it * 16;
        const int c4 = (tid & 15) * 4;
        const float4 f = *(const float4*)&W[(size_t)(k0 + kk) * HEAD + h0 + c4];
        Ts[kk][c4 + 0] = f.x; Ts[kk][c4 + 1] = f.y;
        Ts[kk][c4 + 2] = f.z; Ts[kk][c4 + 3] = f.w;
    }
    __syncthreads();
    const int hr  = tid >> 2;
    const int kc0 = (tid & 3) * 16;
    union { unsigned short s[16]; uint4 q[2]; } tmp;
    #pragma unroll
    for (int i = 0; i < 16; ++i) tmp.s[i] = f2bf(Ts[kc0 + i][hr]);
    unsigned short* dst = &Wt[(size_t)w * HEAD * EMB + (size_t)(h0 + hr) * EMB + k0 + kc0];
    ((uint4*)dst)[0] = tmp.q[0];
    ((uint4*)dst)[1] = tmp.q[1];
}

// ---------------------------------------------------------------------------
// QKV projection v3: SINGLE-WAVE blocks, no barriers (wave-coherent LDS),
// s_waitcnt(0) sync + one-full-step prefetch distance (the pattern proven in
// the attention kernel). BM=32 tokens (2 m-tiles), BK=32, 16 MFMA/step.
// grid (256, 3) = 768 blocks = 3 independent waves/CU (R6-R8: 2-wave blocks
// with 2 barriers/step exposed ~600 cyc of HBM latency every step -> ~35us).
// ---------------------------------------------------------------------------
__global__ __launch_bounds__(64, 1)
void proj_kernel(const float* __restrict__ x, const unsigned short* __restrict__ Wt,
                 unsigned short* __restrict__ qb, unsigned short* __restrict__ kb,
                 unsigned short* __restrict__ vt) {
    __shared__ __align__(16) char smem[24576];
    char* Ab = smem;            // 2 x 4KB : x tile [32 tok][128B] fp32, swizzled
    char* Bb = smem + 8192;     // 2 x 8KB : W tile [128 h][64B] bf16, swizzled

    const int wsel = blockIdx.y;
    const int lane = threadIdx.x;
    const int p = lane >> 4, c = lane & 15;
    const int m0 = blockIdx.x * 32;
    const unsigned short* Wp = Wt + (size_t)wsel * HEAD * EMB;

    const int u7  = c & 7;                 // A-row swizzle key (row&7 == c&7)
    const int u2c = (c ^ (c >> 2)) & 3;    // B-row swizzle key

    auto stage = [&](int bi, int ks) {
        #pragma unroll
        for (int i = 0; i < 4; ++i) {      // A: 32 rows x 128B = 4KB
            const int f = i * 64 + lane;
            const int r = f >> 3, s = f & 7, q = s ^ (r & 7);
            cp16(&x[(size_t)(m0 + r) * EMB + ks * 32 + q * 4],
                 Ab + bi * 4096 + i * 1024);
        }
        #pragma unroll
        for (int i = 0; i < 8; ++i) {      // B: 128 rows x 64B = 8KB
            const int f = i * 64 + lane;
            const int h = f >> 2, s = f & 3, q = s ^ ((h ^ (h >> 2)) & 3);
            cp16(&Wp[(size_t)h * EMB + ks * 32 + q * 8],
                 Bb + bi * 8192 + i * 1024);
        }
    };
    auto xfrag = [&](const char* Ac, int r) {   // row r -> packed bf16x8
        const float4 a0 = *(const float4*)(Ac + r * 128 + (((2 * p)     ^ u7) * 16));
        const float4 a1 = *(const float4*)(Ac + r * 128 + (((2 * p + 1) ^ u7) * 16));
        union { unsigned u[4]; bf16x8 v; } xf;
        xf.u[0] = pk2(a0.x, a0.y); xf.u[1] = pk2(a0.z, a0.w);
        xf.u[2] = pk2(a1.x, a1.y); xf.u[3] = pk2(a1.z, a1.w);
        return xf.v;
    };

    f32x4 acc[2][8];                       // [m-tile or n-tile][8 h-tiles]
    #pragma unroll
    for (int i = 0; i < 2; ++i)
        #pragma unroll
        for (int j = 0; j < 8; ++j) acc[i][j] = (f32x4){0.f, 0.f, 0.f, 0.f};

    stage(0, 0);
    for (int ks = 0; ks < 32; ++ks) {
        const int cur = ks & 1;
        __builtin_amdgcn_s_waitcnt(0);     // drain stage(ks), issued one step ago
        const char* Ac = Ab + cur * 4096;
        const char* Bc = Bb + cur * 8192;
        bf16x8 xv[2], wf[8];
        #pragma unroll
        for (int mi = 0; mi < 2; ++mi) xv[mi] = xfrag(Ac, mi * 16 + c);
        #pragma unroll
        for (int nt = 0; nt < 8; ++nt)
            wf[nt] = *(const bf16x8*)(Bc + (nt * 16 + c) * 64 + ((p ^ u2c) * 16));
        if (ks + 1 < 32) stage(cur ^ 1, ks + 1);   // prefetch: covered by this step
        if (wsel < 2) {
            #pragma unroll
            for (int mi = 0; mi < 2; ++mi)
                #pragma unroll
                for (int nt = 0; nt < 8; ++nt)
                    acc[mi][nt] = __builtin_amdgcn_mfma_f32_16x16x32_bf16(xv[mi], wf[nt], acc[mi][nt], 0, 0, 0);
        } else {
            #pragma unroll
            for (int n2 = 0; n2 < 2; ++n2)
                #pragma unroll
                for (int mt = 0; mt < 8; ++mt)
                    acc[n2][mt] = __builtin_amdgcn_mfma_f32_16x16x32_bf16(wf[mt], xv[n2], acc[n2][mt], 0, 0, 0);
        }
    }

    if (wsel < 2) {
        // C[m = token = m0 + mi*16 + p*4 + rr][n = h = nt*16 + c]
        unsigned short* outp = (wsel == 0) ? qb : kb;
        #pragma unroll
        for (int mi = 0; mi < 2; ++mi)
            #pragma unroll
            for (int rr = 0; rr < 4; ++rr) {
                unsigned short* orow = outp + (size_t)(m0 + mi * 16 + p * 4 + rr) * HEAD + c;
                #pragma unroll
                for (int nt = 0; nt < 8; ++nt)
                    orow[nt * 16] = f2bf(acc[mi][nt][rr]);
            }
    } else {
        // C[m = h = mt*16 + p*4 + rr][n = token = m0 + n2*16 + c] -> vt[b][h][t]
        const int bidx = m0 >> 11;
        const int tl   = m0 & (CTX - 1);
        unsigned short* vbp = vt + (size_t)bidx * HEAD * CTX;
        #pragma unroll
        for (int mt = 0; mt < 8; ++mt)
            #pragma unroll
            for (int rr = 0; rr < 4; ++rr) {
                const int h = mt * 16 + p * 4 + rr;
                #pragma unroll
                for (int n2 = 0; n2 < 2; ++n2)
                    vbp[(size_t)h * CTX + tl + n2 * 16 + c] = f2bf(acc[n2][mt][rr]);
            }
    }
}

// ---------------------------------------------------------------------------
// Split-KV flash attention (R7 v1 — proven fastest). Block = 256 threads
// (4 waves) = 64 q rows, one 512-kv chunk (<=8 steps of 64). K/V staged via
// global_load_lds, double-buffered (64KB LDS). grid (80, 4).
// ---------------------------------------------------------------------------
__global__ __launch_bounds__(256, 2)
void attn_split_kernel(const unsigned short* __restrict__ qb,
                       const unsigned short* __restrict__ kb,
                       const unsigned short* __restrict__ vt,
                       unsigned short* __restrict__ pO,
                       float* __restrict__ pM, float* __restrict__ pL) {
    __shared__ __align__(16) char smem[65536];
    char* Kb = smem;            // 2 x 16KB : [64 kv][128 h] bf16
    char* Vb = smem + 32768;    // 2 x 16KB : [128 h][64 kv] bf16

    const int g = blockIdx.x;   // 0..79
    const int b = blockIdx.y;
    int T, ch;
    if (g < 8)       { T = g;                ch = 0; }
    else if (g < 24) { T = 8  + ((g - 8) >> 1);  ch = (g - 8) & 1; }
    else if (g < 48) { T = 16 + (g - 24) / 3;    ch = (g - 24) % 3; }
    else             { T = 24 + ((g - 48) >> 2); ch = (g - 48) & 3; }
    const int nch    = (T >> 3) + 1;
    const int kstart = ch * 512;
    const int kend   = min(kstart + 512, 64 * (T + 1));
    const int nsteps = (kend - kstart) >> 6;
    const bool lastchunk = (ch == nch - 1);

    const int tid  = threadIdx.x;
    const int wv   = tid >> 6;
    const int lane = tid & 63;
    const int p = lane >> 4, c = lane & 15;
    const int t0 = T * 64;
    const int qg = t0 + wv * 16 + c;
    const int u7 = c & 7;

    const unsigned short* kbat = kb + (size_t)b * CTX * HEAD;
    const unsigned short* vbat = vt + (size_t)b * HEAD * CTX;

    bf16x8 qf[4];
    #pragma unroll
    for (int ks = 0; ks < 4; ++ks)
        qf[ks] = *(const bf16x8*)&qb[((size_t)b * CTX + t0 + wv * 16 + c) * HEAD + ks * 32 + p * 8];

    f32x4 o[8];
    #pragma unroll
    for (int i = 0; i < 8; ++i) o[i] = (f32x4){0.f, 0.f, 0.f, 0.f};
    float m = -FINF, l = 0.f;

    const int  slA = 32 * (p & 1) + c;
    const int  slB = slA + 16;
    const bool thi = (p >> 1) != 0;
    const float scale2 = 0.08838834764831845f * 1.44269504088896340f;  // 1/sqrt(128)*log2e

    auto stage = [&](int bi, int js) {
        const unsigned short* kg = kbat + (size_t)(kstart + js * 64) * HEAD;
        #pragma unroll
        for (int i = 0; i < 4; ++i) {      // K: 64 rows x 256B
            const int f = i * 256 + tid;
            const int r = f >> 4, s = f & 15, q = s ^ (r & 7);
            cp16(kg + (size_t)r * HEAD + q * 8, Kb + bi * 16384 + (f >> 6) * 1024);
        }
        const unsigned short* vg = vbat + kstart + js * 64;
        #pragma unroll
        for (int i = 0; i < 4; ++i) {      // V: 128 rows x 128B
            const int f = i * 256 + tid;
            const int r = f >> 3, s = f & 7, q = s ^ (r & 7);
            cp16(vg + (size_t)r * CTX + q * 8, Vb + bi * 16384 + (f >> 6) * 1024);
        }
    };

    stage(0, 0);
    for (int js = 0; js < nsteps; ++js) {
        const int cur = js & 1;
        __builtin_amdgcn_s_waitcnt(0);
        __syncthreads();                   // buf[cur] staged by all waves

        bf16x8 kfr[4][4];
        #pragma unroll
        for (int nt = 0; nt < 4; ++nt) {
            const char* rp = Kb + cur * 16384 + (nt * 16 + c) * 256;
            #pragma unroll
            for (int ks = 0; ks < 4; ++ks)
                kfr[nt][ks] = *(const bf16x8*)(rp + (((ks * 4 + p) ^ u7) * 16));
        }
        if (js + 1 < nsteps) stage(cur ^ 1, js + 1);

        f32x4 st[4];
        #pragma unroll
        for (int nt = 0; nt < 4; ++nt) st[nt] = (f32x4){0.f, 0.f, 0.f, 0.f};
        #pragma unroll
        for (int ks = 0; ks < 4; ++ks)
            #pragma unroll
            for (int nt = 0; nt < 4; ++nt)
                st[nt] = __builtin_amdgcn_mfma_f32_16x16x32_bf16(kfr[nt][ks], qf[ks], st[nt], 0, 0, 0);

        bf16x8 vfr[2][8];
        #pragma unroll
        for (int mt = 0; mt < 8; ++mt) {
            const char* rp = Vb + cur * 16384 + (mt * 16 + c) * 128;
            #pragma unroll
            for (int ch2 = 0; ch2 < 2; ++ch2)
                vfr[ch2][mt] = *(const bf16x8*)(rp + (((ch2 * 4 + p) ^ u7) * 16));
        }

        float s[4][4];
        float lm = -FINF;
        if (lastchunk && js == nsteps - 1) {
            #pragma unroll
            for (int nt = 0; nt < 4; ++nt)
                #pragma unroll
                for (int r = 0; r < 4; ++r) {
                    const int kv = kstart + js * 64 + nt * 16 + p * 4 + r;
                    float v = st[nt][r] * scale2;
                    v = (kv <= qg) ? v : -FINF;
                    s[nt][r] = v;
                    lm = fmaxf(lm, v);
                }
        } else {
            #pragma unroll
            for (int nt = 0; nt < 4; ++nt)
                #pragma unroll
                for (int r = 0; r < 4; ++r) {
                    const float v = st[nt][r] * scale2;
                    s[nt][r] = v;
                    lm = fmaxf(lm, v);
                }
        }
        lm = fmaxf(lm, __shfl_xor(lm, 16, 64));
        lm = fmaxf(lm, __shfl_xor(lm, 32, 64));
        const float m_new = fmaxf(m, lm);
        const float alpha = fexp2(m - m_new);
        float ls = 0.f;
        #pragma unroll
        for (int nt = 0; nt < 4; ++nt)
            #pragma unroll
            for (int r = 0; r < 4; ++r) {
                const float pv = fexp2(s[nt][r] - m_new);
                s[nt][r] = pv;
                ls += pv;
            }
        ls += __shfl_xor(ls, 16, 64);
        ls += __shfl_xor(ls, 32, 64);
        l = l * alpha + ls;
        m = m_new;
        #pragma unroll
        for (int i = 0; i < 8; ++i) {
            o[i][0] *= alpha; o[i][1] *= alpha;
            o[i][2] *= alpha; o[i][3] *= alpha;
        }
        #pragma unroll
        for (int ch2 = 0; ch2 < 2; ++ch2) {
            const unsigned pa0 = pk2(s[2*ch2][0],     s[2*ch2][1]);
            const unsigned pb0 = pk2(s[2*ch2][2],     s[2*ch2][3]);
            const unsigned pa1 = pk2(s[2*ch2 + 1][0], s[2*ch2 + 1][1]);
            const unsigned pb1 = pk2(s[2*ch2 + 1][2], s[2*ch2 + 1][3]);
            const unsigned u0a = __shfl((int)pa0, slA, 64), u0b = __shfl((int)pa1, slA, 64);
            const unsigned u1a = __shfl((int)pb0, slA, 64), u1b = __shfl((int)pb1, slA, 64);
            const unsigned u2a = __shfl((int)pa0, slB, 64), u2b = __shfl((int)pa1, slB, 64);
            const unsigned u3a = __shfl((int)pb0, slB, 64), u3b = __shfl((int)pb1, slB, 64);
            union { unsigned u[4]; bf16x8 v; } pf;
            pf.u[0] = thi ? u0b : u0a;
            pf.u[1] = thi ? u1b : u1a;
            pf.u[2] = thi ? u2b : u2a;
            pf.u[3] = thi ? u3b : u3a;
            #pragma unroll
            for (int mt = 0; mt < 8; ++mt)
                o[mt] = __builtin_amdgcn_mfma_f32_16x16x32_bf16(vfr[ch2][mt], pf.v, o[mt], 0, 0, 0);
        }
    }

    const size_t pbase = (size_t)(b * 32 + T) * 4 + ch;
    unsigned short* po = pO + pbase * (64 * 128) + (wv * 16 + c) * 128;
    #pragma unroll
    for (int mt = 0; mt < 8; ++mt) {
        union { unsigned short sh[4]; uint2 u; } t;
        #pragma unroll
        for (int r = 0; r < 4; ++r) t.sh[r] = f2bf(o[mt][r]);
        *(uint2*)&po[mt * 16 + p * 4] = t.u;
    }
    if (p == 0) {
        pM[pbase * 64 + wv * 16 + c] = m;
        pL[pbase * 64 + wv * 16 + c] = l;
    }
}

// ---------------------------------------------------------------------------
// Merge up to 4 partial chunks (R7). grid (32, 4), 256 threads.
// ---------------------------------------------------------------------------
__global__ __launch_bounds__(256)
void attn_merge_kernel(const unsigned short* __restrict__ pO,
                       const float* __restrict__ pM, const float* __restrict__ pL,
                       float* __restrict__ out) {
    const int T = blockIdx.x, b = blockIdx.y;
    const int nch = (T >> 3) + 1;
    const int tid = threadIdx.x;
    const int r   = tid >> 2;
    const int c0  = (tid & 3) * 32;
    const size_t base = (size_t)(b * 32 + T) * 4;

    float mv[4], lv[4];
    float M = -FINF;
    #pragma unroll
    for (int i = 0; i < 4; ++i) {
        if (i < nch) { mv[i] = pM[(base + i) * 64 + r]; lv[i] = pL[(base + i) * 64 + r]; }
        else         { mv[i] = -FINF;                   lv[i] = 0.f; }
        M = fmaxf(M, mv[i]);
    }
    float w[4], L = 0.f;
    #pragma unroll
    for (int i = 0; i < 4; ++i) { w[i] = fexp2(mv[i] - M); L += w[i] * lv[i]; }
    const float inv = 1.f / L;

    float acc[32];
    #pragma unroll
    for (int j = 0; j < 32; ++j) acc[j] = 0.f;
    #pragma unroll
    for (int i = 0; i < 4; ++i) {
        if (i < nch) {
            const unsigned* s32 = (const unsigned*)(pO + (base + i) * (64 * 128) + r * 128 + c0);
            const float wi = w[i];
            #pragma unroll
            for (int jw = 0; jw < 16; ++jw) {
                const unsigned u = s32[jw];
                acc[2 * jw]     += wi * bf2f(u & 0xffffu);
                acc[2 * jw + 1] += wi * bf2f(u >> 16);
            }
        }
    }
    float* orow = out + ((size_t)b * CTX + T * 64 + r) * HEAD + c0;
    #pragma unroll
    for (int j4 = 0; j4 < 8; ++j4) {
        float4 ov = make_float4(acc[4*j4] * inv, acc[4*j4+1] * inv,
                                acc[4*j4+2] * inv, acc[4*j4+3] * inv);
        *(float4*)&orow[4 * j4] = ov;
    }
}

// ---------------------------------------------------------------------------
// Fallback attention (R6): single-wave blocks, used if ws too small for split.
// ---------------------------------------------------------------------------
__global__ __launch_bounds__(64, 1)
void attn_kernel(const unsigned short* __restrict__ qb,
                 const unsigned short* __restrict__ kb,
                 const unsigned short* __restrict__ vt,
                 float* __restrict__ out) {
    __shared__ __align__(16) char smem[65536];
    char* Kb = smem;
    char* Vb = smem + 32768;
    const int bx   = blockIdx.x;
    const int b    = bx & 3;
    const int tile = 127 - (bx >> 2);
    const int lane = threadIdx.x;
    const int p = lane >> 4, c = lane & 15;
    const int t0 = tile * 16;
    const int qg = t0 + c;
    const int u7 = c & 7;
    const unsigned short* kbat = kb + (size_t)b * CTX * HEAD;
    const unsigned short* vbat = vt + (size_t)b * HEAD * CTX;
    bf16x8 qf[4];
    #pragma unroll
    for (int ks = 0; ks < 4; ++ks)
        qf[ks] = *(const bf16x8*)&qb[((size_t)b * CTX + t0 + c) * HEAD + ks * 32 + p * 8];
    f32x4 o[8];
    #pragma unroll
    for (int i = 0; i < 8; ++i) o[i] = (f32x4){0.f, 0.f, 0.f, 0.f};
    float m = -FINF, l = 0.f;
    const int  slA = 32 * (p & 1) + c;
    const int  slB = slA + 16;
    const bool thi = (p >> 1) != 0;
    const int  nsteps = (tile + 4) >> 2;
    const float scale2 = 0.08838834764831845f * 1.44269504088896340f;
    auto stage = [&](int bi, int js) {
        const unsigned short* kg = kbat + (size_t)(js * 64) * HEAD;
        #pragma unroll
        for (int i = 0; i < 16; ++i) {
            const int f = i * 64 + lane;
            const int r = f >> 4, s = f & 15, q = s ^ (r & 7);
            cp16(kg + (size_t)r * HEAD + q * 8, Kb + bi * 16384 + i * 1024);
        }
        #pragma unroll
        for (int i = 0; i < 16; ++i) {
            const int f = i * 64 + lane;
            const int r = f >> 3, s = f & 7, q = s ^ (r & 7);
            cp16(vbat + (size_t)r * CTX + js * 64 + q * 8, Vb + bi * 16384 + i * 1024);
        }
    };
    stage(0, 0);
    for (int js = 0; js < nsteps; ++js) {
        const int cur = js & 1;
        __builtin_amdgcn_s_waitcnt(0);
        bf16x8 kfr[4][4], vfr[2][8];
        #pragma unroll
        for (int nt = 0; nt < 4; ++nt) {
            const char* rp = Kb + cur * 16384 + (nt * 16 + c) * 256;
            #pragma unroll
            for (int ks = 0; ks < 4; ++ks)
                kfr[nt][ks] = *(const bf16x8*)(rp + (((ks * 4 + p) ^ u7) * 16));
        }
        #pragma unroll
        for (int mt = 0; mt < 8; ++mt) {
            const char* rp = Vb + cur * 16384 + (mt * 16 + c) * 128;
            #pragma unroll
            for (int ch = 0; ch < 2; ++ch)
                vfr[ch][mt] = *(const bf16x8*)(rp + (((ch * 4 + p) ^ u7) * 16));
        }
        if (js + 1 < nsteps) stage(cur ^ 1, js + 1);
        const int c0 = js * 64;
        f32x4 st[4];
        #pragma unroll
        for (int nt = 0; nt < 4; ++nt) st[nt] = (f32x4){0.f, 0.f, 0.f, 0.f};
        #pragma unroll
        for (int ks = 0; ks < 4; ++ks)
            #pragma unroll
            for (int nt = 0; nt < 4; ++nt)
                st[nt] = __builtin_amdgcn_mfma_f32_16x16x32_bf16(kfr[nt][ks], qf[ks], st[nt], 0, 0, 0);
        float s[4][4];
        float lm = -FINF;
        if (js == nsteps - 1) {
            #pragma unroll
            for (int nt = 0; nt < 4; ++nt)
                #pragma unroll
                for (int r = 0; r < 4; ++r) {
                    const int kv = c0 + nt * 16 + p * 4 + r;
                    float v = st[nt][r] * scale2;
                    v = (kv <= qg) ? v : -FINF;
                    s[nt][r] = v;
                    lm = fmaxf(lm, v);
                }
        } else {
            #pragma unroll
            for (int nt = 0; nt < 4; ++nt)
                #pragma unroll
                for (int r = 0; r < 4; ++r) {
                    const float v = st[nt][r] * scale2;
                    s[nt][r] = v;
                    lm = fmaxf(lm, v);
                }
        }
        lm = fmaxf(lm, __shfl_xor(lm, 16, 64));
        lm = fmaxf(lm, __shfl_xor(lm, 32, 64));
        const float m_new = fmaxf(m, lm);
        const float alpha = fexp2(m - m_new);
        float ls = 0.f;
        #pragma unroll
        for (int nt = 0; nt < 4; ++nt)
            #pragma unroll
            for (int r = 0; r < 4; ++r) {
                const float pv = fexp2(s[nt][r] - m_new);
                s[nt][r] = pv;
                ls += pv;
            }
        ls += __shfl_xor(ls, 16, 64);
        ls += __shfl_xor(ls, 32, 64);
        l = l * alpha + ls;
        m = m_new;
        #pragma unroll
        for (int i = 0; i < 8; ++i) {
            o[i][0] *= alpha; o[i][1] *= alpha;
            o[i][2] *= alpha; o[i][3] *= alpha;
        }
        #pragma unroll
        for (int ch = 0; ch < 2; ++ch) {
            const unsigned pa0 = pk2(s[2*ch][0],     s[2*ch][1]);
            const unsigned pb0 = pk2(s[2*ch][2],     s[2*ch][3]);
            const unsigned pa1 = pk2(s[2*ch + 1][0], s[2*ch + 1][1]);
            const unsigned pb1 = pk2(s[2*ch + 1][2], s[2*ch + 1][3]);
            const unsigned u0a = __shfl((int)pa0, slA, 64), u0b = __shfl((int)pa1, slA, 64);
            const unsigned u1a = __shfl((int)pb0, slA, 64), u1b = __shfl((int)pb1, slA, 64);
            const unsigned u2a = __shfl((int)pa0, slB, 64), u2b = __shfl((int)pa1, slB, 64);
            const unsigned u3a = __shfl((int)pb0, slB, 64), u3b = __shfl((int)pb1, slB, 64);
            union { unsigned u[4]; bf16x8 v; } pf;
            pf.u[0] = thi ? u0b : u0a;
            pf.u[1] = thi ? u1b : u1a;
            pf.u[2] = thi ? u2b : u2a;
            pf.u[3] = thi ? u3b : u3a;
            #pragma unroll
            for (int mt = 0; mt < 8; ++mt)
                o[mt] = __builtin_amdgcn_mfma_f32_16x16x32_bf16(vfr[ch][mt], pf.v, o[mt], 0, 0, 0);
        }
    }
    const float linv = 1.f / l;
    float* orow = out + ((size_t)b * CTX + t0 + c) * HEAD;
    #pragma unroll
    for (int mt = 0; mt < 8; ++mt) {
        float4 ov = make_float4(o[mt][0] * linv, o[mt][1] * linv,
                                o[mt][2] * linv, o[mt][3] * linv);
        *(float4*)&orow[mt * 16 + p * 4] = ov;
    }
}

// ---------------------------------------------------------------------------
extern "C" void kernel_launch(void* const* d_in, const int* in_sizes, int n_in,
                              void* d_out, int out_size, void* d_ws, size_t ws_size,
                              hipStream_t stream) {
    const float* x  = (const float*)d_in[0];
    const float* Wq = (const float*)d_in[1];
    const float* Wk = (const float*)d_in[2];
    const float* Wv = (const float*)d_in[3];
    float* out = (float*)d_out;

    unsigned short* Wt = (unsigned short*)d_ws;                 // 3*128*1024
    unsigned short* qb = Wt + (size_t)3 * HEAD * EMB;           // 8192*128
    unsigned short* kb = qb + (size_t)BATCH * CTX * HEAD;
    unsigned short* vt = kb + (size_t)BATCH * CTX * HEAD;
    unsigned short* pO = vt + (size_t)BATCH * CTX * HEAD;       // 4*32*4*64*128 bf16
    float* pM = (float*)(pO + (size_t)BATCH * 32 * 4 * 64 * 128);
    float* pL = pM + (size_t)BATCH * 32 * 4 * 64;

    const size_t need = (size_t)((char*)(pL + BATCH * 32 * 4 * 64) - (char*)d_ws);

    transpose_w_kernel<<<dim3(16, 2, 3), 256, 0, stream>>>(Wq, Wk, Wv, Wt);
    proj_kernel<<<dim3((BATCH * CTX) / 32, 3), 64, 0, stream>>>(x, Wt, qb, kb, vt);
    if (ws_size >= need) {
        attn_split_kernel<<<dim3(80, 4), 256, 0, stream>>>(qb, kb, vt, pO, pM, pL);
        attn_merge_kernel<<<dim3(32, 4), 256, 0, stream>>>(pO, pM, pL, out);
    } else {
        attn_kernel<<<BATCH * (CTX / 16), 64, 0, stream>>>(qb, kb, vt, out);
    }
}